// Round 6
// baseline (316.434 us; speedup 1.0000x reference)
//
#include <hip/hip_runtime.h>

#define EPS_K 1e-7f

typedef __attribute__((ext_vector_type(8))) short          frag8;  // 8 bf16 (4 VGPRs)
typedef __attribute__((ext_vector_type(4))) float          accf4;  // 16x16 MFMA C/D
typedef __attribute__((ext_vector_type(4))) unsigned short us4;    // 8B LDS read

__device__ __forceinline__ unsigned f2bf(float f) {
  union { float f; unsigned u; } v; v.f = f;
  unsigned u = v.u;
  u += 0x7FFFu + ((u >> 16) & 1u);   // RNE
  return u >> 16;
}
__device__ __forceinline__ float bf2f(unsigned short s) {
  union { unsigned u; float f; } v; v.u = ((unsigned)s) << 16;
  return v.f;
}
__device__ __forceinline__ unsigned pk_bf16(float lo, float hi) {
  return f2bf(lo) | (f2bf(hi) << 16);
}

// ---------------------------------------------------------------------------
// Pre-pass: W (2048,32,32) f32 [s][t][u]  ->  Wbf bf16 [s][u][t] (4 MB in ws)
// ---------------------------------------------------------------------------
__global__ __launch_bounds__(256) void wbf_prep(
    const float* __restrict__ Wt, unsigned short* __restrict__ Wbf)
{
  __shared__ unsigned short tile[32 * 33];     // [t][u], pad 33
  const int s   = blockIdx.x;
  const int tid = threadIdx.x;
  {
    const int t  = tid >> 3;
    const int uc = tid & 7;                    // u-chunk of 4
    const float4 v = *(const float4*)(Wt + s * 1024 + t * 32 + 4 * uc);
    tile[t * 33 + 4 * uc + 0] = (unsigned short)f2bf(v.x);
    tile[t * 33 + 4 * uc + 1] = (unsigned short)f2bf(v.y);
    tile[t * 33 + 4 * uc + 2] = (unsigned short)f2bf(v.z);
    tile[t * 33 + 4 * uc + 3] = (unsigned short)f2bf(v.w);
  }
  __syncthreads();
  {
    const int u  = tid >> 3;
    const int tc = tid & 7;                    // t-chunk of 4
    uint2 d;
    d.x = (unsigned)tile[(4 * tc + 0) * 33 + u] | ((unsigned)tile[(4 * tc + 1) * 33 + u] << 16);
    d.y = (unsigned)tile[(4 * tc + 2) * 33 + u] | ((unsigned)tile[(4 * tc + 3) * 33 + u] << 16);
    *(uint2*)(Wbf + s * 1024 + u * 32 + 4 * tc) = d;
  }
}

// ---------------------------------------------------------------------------
// Main kernel. inputs/mask (512,32,2048), W (2048,32,32), b (2048,32), out (512,32)
// Tile: 16 b x 32 t x 32 s  ->  every (b,t) row read is 128B CONTIGUOUS
// (R6 theory: DRAM row locality / full 128B L2 lines; was 64B in R2-R5).
//
// Per s: D[u][b] via mfma_f32_16x16x32_bf16, two u-halves.
//   A[m=lane&15][k=(lane>>4)*8+j] = W[s][t=k][u=uh*16+m]  (from Wbf [s][u][t])
//   B[k=(lane>>4)*8+j][n=lane&15] = x[b=n][t=k]           (from LDS)
//   C/D: col=lane&15=b, row=(lane>>4)*4+r -> u = uh*16 + 4*q + r  (m89/m91)
//
// LDS x-tile: 16B chunk(slot s, b, q) at index slot*64 + b*4 + q, holding
// x[b][t=8q+j], j=0..7 bf16. B-frag = 1 ds_read_b128 (floor-distribution),
// O-update = 2 ds_read_b64, staging = 4 ds_write_b128 per thread-iter.
// ---------------------------------------------------------------------------
template <bool WBF, bool USE_WS>
__global__ __launch_bounds__(256, 5) void attn_fused(
    const float* __restrict__ inp,
    const float* __restrict__ msk,
    const float* __restrict__ Wt,
    const unsigned short* __restrict__ Wbf,
    const float* __restrict__ bias,
    float* __restrict__ part,
    float* __restrict__ out)
{
  __shared__ unsigned short x_us[16384];       // 32 KB

  const int tid = threadIdx.x;
  const int st  = blockIdx.x >> 5;             // s-tile 0..63
  const int bg  = blockIdx.x & 31;             // b-group 0..31 (16 b each)
  const int s0  = st * 32;

  // ---- stage x = inp*msk: thread owns (b, 8 t, 4 s); rows read as 128B ----
  #pragma unroll
  for (int iter = 0; iter < 2; ++iter) {
    const int idx = iter * 256 + tid;
    const int sq  = idx & 7;                   // 16B sub-segment of the 128B row
    const int q   = (idx >> 3) & 3;            // t-block of 8
    const int b   = idx >> 5;                  // 0..15
    const size_t rbase = ((size_t)(bg * 16 + b) * 32 + 8 * q) * 2048 + s0 + 4 * sq;
    const float* ip = inp + rbase;
    const float* mp = msk + rbase;
    float4 vi4[8], vm4[8];
    #pragma unroll
    for (int j = 0; j < 8; ++j) vi4[j] = *(const float4*)(ip + (size_t)j * 2048);
    #pragma unroll
    for (int j = 0; j < 8; ++j) vm4[j] = *(const float4*)(mp + (size_t)j * 2048);
    const float* vi = (const float*)vi4;
    const float* vm = (const float*)vm4;
    #pragma unroll
    for (int i = 0; i < 4; ++i) {              // s within the 16B quad
      uint4 c;
      c.x = pk_bf16(vi[0 * 4 + i] * vm[0 * 4 + i], vi[1 * 4 + i] * vm[1 * 4 + i]);
      c.y = pk_bf16(vi[2 * 4 + i] * vm[2 * 4 + i], vi[3 * 4 + i] * vm[3 * 4 + i]);
      c.z = pk_bf16(vi[4 * 4 + i] * vm[4 * 4 + i], vi[5 * 4 + i] * vm[5 * 4 + i]);
      c.w = pk_bf16(vi[6 * 4 + i] * vm[6 * 4 + i], vi[7 * 4 + i] * vm[7 * 4 + i]);
      const int slot = 4 * sq + i;
      *(uint4*)(x_us + (size_t)(slot * 64 + b * 4 + q) * 8) = c;
    }
  }
  __syncthreads();

  const int lane = tid & 63;
  const int wv   = tid >> 6;                   // wave -> s = s0 + wv*8 + si
  const int m    = lane & 15;                  // b (B n, C col) / u-in-half (A m)
  const int q    = lane >> 4;                  // k-quad / C row group

  float O[8];
  #pragma unroll
  for (int r = 0; r < 8; ++r) O[r] = 0.f;

  #pragma unroll
  for (int si = 0; si < 8; ++si) {
    const int slot = wv * 8 + si;
    const int s    = s0 + slot;

    // A-frags (two u-halves), 16B each, 1 KB contiguous per wave-instr
    frag8 a0, a1;
    if (WBF) {
      const unsigned short* wp = Wbf + s * 1024 + m * 32 + 8 * q;
      a0 = *(const frag8*)(wp);                // u = m
      a1 = *(const frag8*)(wp + 512);          // u = 16 + m
    } else {
      const float* Wp = Wt + s * 1024;
      #pragma unroll
      for (int j = 0; j < 8; ++j) {
        const int t1 = 8 * q + j;
        a0[j] = (short)f2bf(Wp[t1 * 32 + m]);
        a1[j] = (short)f2bf(Wp[t1 * 32 + 16 + m]);
      }
    }

    // B-frag: x[b=m][t=8q+j] -> chunk(slot, m, q)
    const frag8 bf = *(const frag8*)(x_us + (size_t)(slot * 64 + m * 4 + q) * 8);

    const float4 bb0 = *(const float4*)(bias + s * 32 + 4 * q);
    const float4 bb1 = *(const float4*)(bias + s * 32 + 16 + 4 * q);
    accf4 acc0, acc1;
    acc0[0] = bb0.x; acc0[1] = bb0.y; acc0[2] = bb0.z; acc0[3] = bb0.w;
    acc1[0] = bb1.x; acc1[1] = bb1.y; acc1[2] = bb1.z; acc1[3] = bb1.w;
    acc0 = __builtin_amdgcn_mfma_f32_16x16x32_bf16(a0, bf, acc0, 0, 0, 0);
    acc1 = __builtin_amdgcn_mfma_f32_16x16x32_bf16(a1, bf, acc1, 0, 0, 0);

    // e = exp(tanh(z)); tanh(z) = 1 - 2/(exp(2z)+1)
    float e[8];
    float ps = 0.f;
    #pragma unroll
    for (int r = 0; r < 4; ++r) {
      const float z  = acc0[r];
      const float e2 = __expf(2.f * z);
      e[r] = __expf(1.f - 2.f / (e2 + 1.f));
      ps  += e[r];
    }
    #pragma unroll
    for (int r = 0; r < 4; ++r) {
      const float z  = acc1[r];
      const float e2 = __expf(2.f * z);
      e[4 + r] = __expf(1.f - 2.f / (e2 + 1.f));
      ps += e[4 + r];
    }
    // sum over u: lanes {m, m+16, m+32, m+48} hold the 4 q-groups
    const float t1s = ps + __shfl_xor(ps, 16, 64);
    const float tot = t1s + __shfl_xor(t1s, 32, 64);
    const float inv = 1.f / (tot + EPS_K);

    // O += att * x ; x[b=m][t=u]: u=4q+r (chunk q>>1) and 16+4q+r (chunk 2+(q>>1))
    const us4 x0 = *(const us4*)(x_us + (size_t)(slot * 64 + m * 4 + (q >> 1)) * 8 + 4 * (q & 1));
    const us4 x1 = *(const us4*)(x_us + (size_t)(slot * 64 + m * 4 + 2 + (q >> 1)) * 8 + 4 * (q & 1));
    #pragma unroll
    for (int r = 0; r < 4; ++r) {
      O[r]     += e[r]     * inv * bf2f(x0[r]);
      O[4 + r] += e[4 + r] * inv * bf2f(x1[r]);
    }
  }

  // ---- cross-wave reduction in LDS (no atomics) ----
  __syncthreads();
  float* red = (float*)x_us;                   // 4 x 512 floats = 8 KB
  #pragma unroll
  for (int r = 0; r < 8; ++r) {
    const int u = (r < 4) ? (4 * q + r) : (16 + 4 * q + (r - 4));
    red[wv * 512 + m * 32 + (u ^ m)] = O[r];   // ^m breaks bank aliasing
  }
  __syncthreads();

  // 256 threads x 2 outputs: block partial = [b(16)][u(32)] = 512 floats
  const int f0 = tid * 2;
  float2 v;
  #pragma unroll
  for (int i = 0; i < 2; ++i) {
    const int f = f0 + i, b = f >> 5, u = f & 31;
    float sum = 0.f;
    #pragma unroll
    for (int w = 0; w < 4; ++w) sum += red[w * 512 + b * 32 + (u ^ b)];
    (&v.x)[i] = sum;
  }
  if (USE_WS) {
    *(float2*)(part + (size_t)st * 16384 + bg * 512 + f0) = v;
  } else {
    float* op = out + bg * 512 + f0;
    atomicAdd(op, v.x);
    atomicAdd(op + 1, v.y);
  }
}

// out[f] = sum over 64 s-tiles of part[st][f]
__global__ __launch_bounds__(256) void reduce_part(
    const float* __restrict__ part, float* __restrict__ out)
{
  const int f = blockIdx.x * 256 + threadIdx.x;   // 64 blocks x 256 = 16384
  float s = 0.f;
  #pragma unroll 8
  for (int st = 0; st < 64; ++st) s += part[(size_t)st * 16384 + f];
  out[f] = s;
}

extern "C" void kernel_launch(void* const* d_in, const int* in_sizes, int n_in,
                              void* d_out, int out_size, void* d_ws, size_t ws_size,
                              hipStream_t stream) {
  const float* inp  = (const float*)d_in[0];   // (512,32,2048) f32
  const float* msk  = (const float*)d_in[1];   // (512,32,2048) f32
  const float* Wt   = (const float*)d_in[2];   // (2048,32,32)  f32
  const float* bias = (const float*)d_in[3];   // (2048,32)     f32
  float* out = (float*)d_out;                  // (512,32)      f32

  const size_t part_sz = (size_t)64 * 16384 * sizeof(float);           // 4 MB
  const size_t wbf_sz  = (size_t)2048 * 1024 * sizeof(unsigned short); // 4 MB

  if (ws_size >= part_sz + wbf_sz) {
    float* part = (float*)d_ws;
    unsigned short* Wbf = (unsigned short*)((char*)d_ws + part_sz);
    wbf_prep<<<dim3(2048), dim3(256), 0, stream>>>(Wt, Wbf);
    attn_fused<true, true><<<dim3(2048), dim3(256), 0, stream>>>(
        inp, msk, Wt, Wbf, bias, part, out);
    reduce_part<<<dim3(64), dim3(256), 0, stream>>>(part, out);
  } else if (ws_size >= part_sz) {
    float* part = (float*)d_ws;
    attn_fused<false, true><<<dim3(2048), dim3(256), 0, stream>>>(
        inp, msk, Wt, nullptr, bias, part, out);
    reduce_part<<<dim3(64), dim3(256), 0, stream>>>(part, out);
  } else {
    (void)hipMemsetAsync(out, 0, (size_t)out_size * sizeof(float), stream);
    attn_fused<false, false><<<dim3(2048), dim3(256), 0, stream>>>(
        inp, msk, Wt, nullptr, bias, nullptr, out);
  }
}